// Round 1
// baseline (376.302 us; speedup 1.0000x reference)
//
#include <hip/hip_runtime.h>

typedef __bf16 bf16;
typedef __bf16 v8bf __attribute__((ext_vector_type(8)));
typedef __bf16 v4bf __attribute__((ext_vector_type(4)));
typedef float f32x4 __attribute__((ext_vector_type(4)));

#define MFMA16x16x32(a, b, c) __builtin_amdgcn_mfma_f32_16x16x32_bf16((a), (b), (c), 0, 0, 0)

// ---------------- prep kernels ----------------
// Wt[o][k] (bf16, 128x256): k<128 -> (w_fuse[:, :128] @ w_h_pw)[o][k]
//                           k>=128 -> (w_fuse[:, 128:] @ w_v_pw)[o][k-128]
__global__ void prep_wt(const float* __restrict__ wfuse,
                        const float* __restrict__ whpw,
                        const float* __restrict__ wvpw,
                        bf16* __restrict__ Wt) {
  int id = blockIdx.x * 256 + threadIdx.x;  // 32768 total, o == blockIdx.x
  int o = id >> 8;
  int k = id & 255;
  const float* fr = wfuse + o * 256 + (k < 128 ? 0 : 128);
  const float* pw = (k < 128) ? whpw : wvpw;
  int ki = k & 127;
  float acc = 0.f;
#pragma unroll 8
  for (int j = 0; j < 128; ++j) acc = fmaf(fr[j], pw[j * 128 + ki], acc);
  Wt[o * 256 + k] = (bf16)acc;
}

// bf16 copies of w_dm1 [32][128] and w_dm2 [128][32]
__global__ void prep_dm(const float* __restrict__ wdm1,
                        const float* __restrict__ wdm2,
                        bf16* __restrict__ W1, bf16* __restrict__ W2) {
  int id = blockIdx.x * 256 + threadIdx.x;  // 8192
  if (id < 4096) W1[id] = (bf16)wdm1[id];
  else           W2[id - 4096] = (bf16)wdm2[id - 4096];
}

// ---------------- fused main kernel ----------------
// Grid: 512 blocks = (b:2) x (hi:64) x (wchunk:4).  Block tile: 5 rows x 80 cols
// = 400 positions (pos = a*80 + col), all 128 output channels.
// GEMM: epi[o][pos] = sum_k Wt[o][k] * cat[k][pos], K=256 streamed as 8 chunks
// of 16 input channels (each contributing dh (k=c) and dv (k=128+c)).
// Wave w owns N-tiles {w, w+8, w+16, w+24<25} with all 8 M(o)-tiles.
__global__ __launch_bounds__(512, 2) void fused_main(
    const float* __restrict__ x,
    const float* __restrict__ whdw,   // [128][5]
    const float* __restrict__ wvdw,   // [128][5]
    const bf16* __restrict__ Wt,      // [128][256]
    const bf16* __restrict__ W1,      // [32][128]
    const bf16* __restrict__ W2,      // [128][32]
    const float* __restrict__ scalep,
    float* __restrict__ out) {
  __shared__ float wdws[2][640];                  // 5120 B (dw-conv weights)
  __shared__ __align__(16) char smem[57600];      // xs+cs  /  es+ts overlay
  float* xs = (float*)smem;                       // [16][5][80] fp32 (25600 B)
  bf16* cs = (bf16*)(smem + 25600);               // [400][40] bf16  (32000 B)

  const int tid = threadIdx.x;
  const int w = tid >> 6;
  const int lane = tid & 63;
  const int ln16 = lane & 15;
  const int q = lane >> 4;

  const int bx = blockIdx.x;
  const int wc = bx & 3;
  const int hi = (bx >> 2) & 63;
  const int b = bx >> 8;
  const int w0 = wc * 80;
  // x element (c, r, col) at: xbase + c*102400 + r*320 + col
  const size_t xbase = (size_t)b * 13107200 + (size_t)(hi * 5) * 320 + (size_t)w0;

  // stage depthwise weights once
  for (int i = tid; i < 1280; i += 512) {
    if (i < 640) wdws[0][i] = whdw[i];
    else         wdws[1][i - 640] = wvdw[i - 640];
  }

  f32x4 acc[4][8];
#pragma unroll
  for (int s = 0; s < 4; ++s)
#pragma unroll
    for (int m = 0; m < 8; ++m) acc[s][m] = (f32x4){0.f, 0.f, 0.f, 0.f};

  // per-thread position for the cat build (threads 400..511 idle there)
  const int cpos = tid;
  int ca = 0, ccol = 0, caw = 0;
  if (cpos < 400) {
    ca = cpos / 80;
    ccol = cpos - ca * 80;
    caw = ccol % 5;
  }

  for (int kk = 0; kk < 8; ++kk) {
    const int c0 = kk * 16;
    __syncthreads();  // prev chunk's cs readers done before overwrite
    // ---- stage x chunk: 16 ch x 5 rows x 80 cols (float4 loads) ----
    for (int i = tid; i < 1600; i += 512) {
      int c = i / 100;
      int rem = i - c * 100;
      int r = rem / 20;
      int c4 = rem - r * 20;
      const float4 v = *(const float4*)(x + xbase + (size_t)((c0 + c) * 102400 + r * 320 + c4 * 4));
      *(float4*)&xs[(c * 5 + r) * 80 + c4 * 4] = v;
    }
    __syncthreads();
    // ---- build cat chunk: cs[pos][l], l<16: dh(c0+l), l>=16: dv(c0+l-16) ----
    if (cpos < 400) {
#pragma unroll 4
      for (int c = 0; c < 16; ++c) {
        const float* xr = &xs[(c * 5 + ca) * 80];
        float dh = 0.f, dv = 0.f;
#pragma unroll
        for (int t = 0; t < 5; ++t) {
          const int d = t - 2;
          // horizontal tap: valid iff (aw+d) in [0,5)
          int okh = (unsigned)(caw + d) < 5u;
          int ih = ccol + d;
          ih = ih < 0 ? 0 : (ih > 79 ? 79 : ih);
          float vh = okh ? xr[ih] : 0.f;
          dh = fmaf(wdws[0][(c0 + c) * 5 + t], vh, dh);
          // vertical tap: valid iff (a+d) in [0,5)
          int okv = (unsigned)(ca + d) < 5u;
          int iv = ca + d;
          iv = iv < 0 ? 0 : (iv > 4 ? 4 : iv);
          float vv = okv ? xs[(c * 5 + iv) * 80 + ccol] : 0.f;
          dv = fmaf(wdws[1][(c0 + c) * 5 + t], vv, dv);
        }
        dh = fmaxf(dh, 0.f) + 0.1f * fminf(dh, 0.f);
        dv = fmaxf(dv, 0.f) + 0.1f * fminf(dv, 0.f);
        cs[cpos * 40 + c] = (bf16)dh;
        cs[cpos * 40 + 16 + c] = (bf16)dv;
      }
    }
    __syncthreads();
    // ---- MFMA: A = Wt rows (global/L2), B = cs (LDS) ----
    v8bf af[8];
    const int koff = kk * 16 + (q & 1) * 8 + (q >> 1) * 128;
#pragma unroll
    for (int m = 0; m < 8; ++m)
      af[m] = *(const v8bf*)(Wt + (m * 16 + ln16) * 256 + koff);
#pragma unroll
    for (int s = 0; s < 4; ++s) {
      const int nt = w + 8 * s;
      if (nt < 25) {
        v8bf bfr = *(const v8bf*)(cs + (nt * 16 + ln16) * 40 + q * 8);
#pragma unroll
        for (int m = 0; m < 8; ++m) acc[s][m] = MFMA16x16x32(af[m], bfr, acc[s][m]);
      }
    }
  }
  __syncthreads();  // all cs readers done; overlay smem with epilogue buffers

  // per-wave private epilogue buffers (no cross-wave traffic, no barriers)
  bf16* es = (bf16*)(smem + w * 4608);            // [16 pos][144] (128 o + pad)
  bf16* ts = (bf16*)(smem + 36864 + w * 1280);    // [16 pos][40]  (32 d + pad)
  const float scl = scalep[0];

#pragma unroll
  for (int s = 0; s < 4; ++s) {
    const int nt = w + 8 * s;
    if (nt < 25) {
      // 1) epi C-frags -> es[pos][o] bf16 (4 consecutive o per b64 store)
#pragma unroll
      for (int m = 0; m < 8; ++m) {
        v4bf v;
        v[0] = (bf16)acc[s][m][0];
        v[1] = (bf16)acc[s][m][1];
        v[2] = (bf16)acc[s][m][2];
        v[3] = (bf16)acc[s][m][3];
        *(v4bf*)(es + ln16 * 144 + m * 16 + q * 4) = v;
      }
      // 2) t = lrelu(Wdm1 @ epi): M=32 (2 tiles), K=128 (4 steps)
      f32x4 tacc[2];
      tacc[0] = (f32x4){0.f, 0.f, 0.f, 0.f};
      tacc[1] = (f32x4){0.f, 0.f, 0.f, 0.f};
#pragma unroll
      for (int ks = 0; ks < 4; ++ks) {
        v8bf bfr = *(const v8bf*)(es + ln16 * 144 + ks * 32 + q * 8);
#pragma unroll
        for (int m2 = 0; m2 < 2; ++m2) {
          v8bf afr = *(const v8bf*)(W1 + (m2 * 16 + ln16) * 128 + ks * 32 + q * 8);
          tacc[m2] = MFMA16x16x32(afr, bfr, tacc[m2]);
        }
      }
      // 3) lrelu(t) -> ts[pos][d] bf16
#pragma unroll
      for (int m2 = 0; m2 < 2; ++m2) {
        v4bf v;
#pragma unroll
        for (int r = 0; r < 4; ++r) {
          float tv = tacc[m2][r];
          tv = fmaxf(tv, 0.f) + 0.1f * fminf(tv, 0.f);
          v[r] = (bf16)tv;
        }
        *(v4bf*)(ts + ln16 * 40 + m2 * 16 + q * 4) = v;
      }
      // 4) dw = Wdm2 @ t (K=32, one step); 5) out = x + scale*epi*sigmoid(dw)
      v8bf tb = *(const v8bf*)(ts + ln16 * 40 + q * 8);
      const int pos = nt * 16 + ln16;
      const int a = pos / 80;
      const int col = pos - a * 80;
      const size_t gb = xbase + (size_t)(a * 320 + col);
#pragma unroll
      for (int m = 0; m < 8; ++m) {
        v8bf afr2 = *(const v8bf*)(W2 + (m * 16 + ln16) * 32 + q * 8);
        f32x4 z = {0.f, 0.f, 0.f, 0.f};
        f32x4 dacc = MFMA16x16x32(afr2, tb, z);
#pragma unroll
        for (int r = 0; r < 4; ++r) {
          const int o = m * 16 + q * 4 + r;
          const float sig = 1.0f / (1.0f + __expf(-dacc[r]));
          const size_t g = gb + (size_t)o * 102400;
          out[g] = x[g] + scl * acc[s][m][r] * sig;
        }
      }
    }
  }
}

// ---------------- launcher ----------------
extern "C" void kernel_launch(void* const* d_in, const int* in_sizes, int n_in,
                              void* d_out, int out_size, void* d_ws, size_t ws_size,
                              hipStream_t stream) {
  (void)in_sizes; (void)n_in; (void)out_size; (void)ws_size;
  const float* x     = (const float*)d_in[0];
  const float* whdw  = (const float*)d_in[1];
  const float* whpw  = (const float*)d_in[2];
  const float* wvdw  = (const float*)d_in[3];
  const float* wvpw  = (const float*)d_in[4];
  const float* wdm1  = (const float*)d_in[5];
  const float* wdm2  = (const float*)d_in[6];
  const float* wfuse = (const float*)d_in[7];
  const float* scale = (const float*)d_in[8];
  // d_in[9] = angRes (constant 5, baked in)

  bf16* Wt = (bf16*)d_ws;          // 128*256 bf16 = 65536 B
  bf16* W1 = Wt + 32768;           // 32*128  bf16 =  8192 B
  bf16* W2 = W1 + 4096;            // 128*32  bf16 =  8192 B

  prep_wt<<<128, 256, 0, stream>>>(wfuse, whpw, wvpw, Wt);
  prep_dm<<<32, 256, 0, stream>>>(wdm1, wdm2, W1, W2);
  fused_main<<<512, 512, 0, stream>>>(x, whdw, wvdw, Wt, W1, W2, scale, (float*)d_out);
}